// Round 2
// baseline (828.561 us; speedup 1.0000x reference)
//
#include <hip/hip_runtime.h>
#include <hip/hip_bf16.h>

#define NN 64
#define BATCH 512
#define SP 60
#define SG 180
#define SEX 10
#define CATD 80
#define NA 5
#define NR 7
#define BB 4
#define OO 8
#define II 8

typedef unsigned long long u64;
typedef unsigned short u16;
typedef unsigned int u32;

// ---- workspace layout (float offsets) ----
#define OFF_Z     0
#define OFF_DZ    327680
#define OFF_HAS   655360
#define OFF_WIHF  688128
#define OFF_WHHF  698928
#define OFF_BIHF  709728
#define OFF_BHHF  709908
#define OFF_WIHB  710088
#define OFF_WHHB  720888
#define OFF_BIHB  731688
#define OFF_BHHB  731868
#define OFF_WF    732048
#define OFF_BF    736848
#define OFF_WB    736908
#define OFF_BB    741708
#define OFF_WA    741768
#define OFF_BA    742368
#define OFF_WC    742373
#define OFF_BC    742493
#define OFF_WU    742494
#define OFF_BU    743334
#define CONV_TOTAL 743341
#define OFF_GIF   743344
#define OFF_GIB   (OFF_GIF + 5898240)
#define OFF_RHOF  (OFF_GIB + 5898240)
#define OFF_RHOB  (OFF_RHOF + 1966080)
#define OFF_ALF   (OFF_RHOB + 1966080)
#define OFF_ALB   (OFF_ALF + 30720)
#define OFF_OSTG  (OFF_ALB + 30720)
#define OUT_TOTAL 232448

__device__ __forceinline__ float us2f(u16 v){
  return __uint_as_float(((u32)v) << 16);
}
__device__ __forceinline__ u16 f2bf(float f){
  __hip_bfloat16 h = __float2bfloat16(f);
  return *reinterpret_cast<u16*>(&h);
}
__device__ __forceinline__ float sigm(float x){ return 1.f/(1.f+__expf(-x)); }
__device__ __forceinline__ float tanh_(float x){
  float ax = fabsf(x);
  float e = __expf(-2.f*ax);
  float t = (1.f - e)/(1.f + e);
  return copysignf(t, x);
}

// has is exactly {0,1}. f32 words: only 0x00000000 / 0x3F800000.
// bf16-pair words: 0x3F803F80 == (1.0,1.0) appears w.p. ~0.81 per pair.
__device__ __forceinline__ int detect_bf16(const u32* w){
  int f = 0;
  for (int i=0;i<256;i++) f |= (w[i] == 0x3F803F80u) ? 1 : 0;
  return f;
}

__global__ __launch_bounds__(256) void conv_in(
  const void* z, const void* dz, const void* has,
  const void* WihF, const void* WhhF, const void* bihF, const void* bhhF,
  const void* WihB, const void* WhhB, const void* bihB, const void* bhhB,
  const void* Wf_, const void* bf_, const void* Wb_, const void* bb_,
  const void* Wa, const void* ba, const void* Wc, const void* bc,
  const void* Wu, const void* bu, float* ws)
{
  const int isbf = detect_bf16((const u32*)has);
  int idx = blockIdx.x*256 + threadIdx.x;
  if (idx >= CONV_TOTAL) return;
  const void* src; int loc;
  if      (idx < OFF_DZ  ){ src=z;    loc=idx-OFF_Z;    }
  else if (idx < OFF_HAS ){ src=dz;   loc=idx-OFF_DZ;   }
  else if (idx < OFF_WIHF){ src=has;  loc=idx-OFF_HAS;  }
  else if (idx < OFF_WHHF){ src=WihF; loc=idx-OFF_WIHF; }
  else if (idx < OFF_BIHF){ src=WhhF; loc=idx-OFF_WHHF; }
  else if (idx < OFF_BHHF){ src=bihF; loc=idx-OFF_BIHF; }
  else if (idx < OFF_WIHB){ src=bhhF; loc=idx-OFF_BHHF; }
  else if (idx < OFF_WHHB){ src=WihB; loc=idx-OFF_WIHB; }
  else if (idx < OFF_BIHB){ src=WhhB; loc=idx-OFF_WHHB; }
  else if (idx < OFF_BHHB){ src=bihB; loc=idx-OFF_BIHB; }
  else if (idx < OFF_WF  ){ src=bhhB; loc=idx-OFF_BHHB; }
  else if (idx < OFF_BF  ){ src=Wf_;  loc=idx-OFF_WF;   }
  else if (idx < OFF_WB  ){ src=bf_;  loc=idx-OFF_BF;   }
  else if (idx < OFF_BB  ){ src=Wb_;  loc=idx-OFF_WB;   }
  else if (idx < OFF_WA  ){ src=bb_;  loc=idx-OFF_BB;   }
  else if (idx < OFF_BA  ){ src=Wa;   loc=idx-OFF_WA;   }
  else if (idx < OFF_WC  ){ src=ba;   loc=idx-OFF_BA;   }
  else if (idx < OFF_BC  ){ src=Wc;   loc=idx-OFF_WC;   }
  else if (idx < OFF_WU  ){ src=bc;   loc=idx-OFF_BC;   }
  else if (idx < OFF_BU  ){ src=Wu;   loc=idx-OFF_WU;   }
  else                    { src=bu;   loc=idx-OFF_BU;   }
  float v = isbf ? us2f(((const u16*)src)[loc]) : ((const float*)src)[loc];
  ws[idx] = v;
}

__global__ __launch_bounds__(256) void conv_out(
  const void* has, const float* ws, void* out)
{
  const int isbf = detect_bf16((const u32*)has);
  int idx = blockIdx.x*256 + threadIdx.x;
  if (idx >= OUT_TOTAL) return;
  float v = ws[OFF_OSTG + idx];
  if (isbf) ((u16*)out)[idx] = f2bf(v);
  else      ((float*)out)[idx] = v;
}

// One block = 4 batch rows of one direction. blocks 0..127 fwd, 128..255 bwd.
__global__ __launch_bounds__(256, 1) void dir_kernel(const int* __restrict__ adj,
                                                     float* __restrict__ ws)
{
  const int tid = threadIdx.x;
  const int bid = blockIdx.x;
  const int bwd = bid >> 7;
  const int b0  = (bid & 127) * BB;
  const int bl  = tid >> 6;     // 0..3 local batch row
  const int n0  = tid & 63;     // hidden unit (active if <60)
  const int bglob = b0 + bl;

  const float* Wih  = ws + (bwd ? OFF_WIHB : OFF_WIHF);
  const float* Whh  = ws + (bwd ? OFF_WHHB : OFF_WHHF);
  const float* bih  = ws + (bwd ? OFF_BIHB : OFF_BIHF);
  const float* bhh  = ws + (bwd ? OFF_BHHB : OFF_BHHF);
  const float* Wcat = ws + (bwd ? OFF_WB   : OFF_WF);
  const float* bcat = ws + (bwd ? OFF_BB   : OFF_BF);
  const float* zc   = ws + OFF_Z;
  const float* dzc  = ws + OFF_DZ;
  const float* hasc = ws + OFF_HAS;
  float* gi    = ws + (bwd ? OFF_GIB  : OFF_GIF);
  float* rho   = ws + (bwd ? OFF_RHOB : OFF_RHOF);
  float* alpha = ws + (bwd ? OFF_ALB  : OFF_ALF);

  __shared__ float sWihT[SP*SG];       // transposed [k][n]
  __shared__ float sWcatT[CATD*SP];    // transposed [k][n]
  __shared__ float sBih[SG];
  __shared__ float sBcat[SP];
  __shared__ float sHas[BB*NN];
  __shared__ float sZ[BB*NN*SEX];
  __shared__ float sDZ[BB*NN*SEX];
  __shared__ __align__(16) float sH[2][BB][SP];
  __shared__ float sRho[BB*SP];
  __shared__ u64 sCol[NN];
  __shared__ u64 sRow[NN];

  // ---- staging ----
  if (tid < NN){
    u64 c = 0ULL, r = 0ULL;
    for (int j=0;j<NN;j++){
      c |= ((u64)(adj[j*NN+tid] != 0)) << j;   // column tid: preds j
      r |= ((u64)(adj[tid*NN+j] != 0)) << j;   // row tid: succs j
    }
    sCol[tid] = c; sRow[tid] = r;
  }
  for (int idx=tid; idx<SG*SP; idx+=256){ int n=idx/SP, k=idx%SP; sWihT[k*SG+n] = Wih[idx]; }
  for (int idx=tid; idx<SP*CATD; idx+=256){ int n=idx/CATD, k=idx%CATD; sWcatT[k*SP+n] = Wcat[idx]; }
  for (int idx=tid; idx<SG; idx+=256) sBih[idx]  = bih[idx];
  for (int idx=tid; idx<SP; idx+=256) sBcat[idx] = bcat[idx];
  for (int idx=tid; idx<BB*NN; idx+=256) sHas[idx] = hasc[(b0 + idx/NN)*NN + (idx%NN)];
  for (int idx=tid; idx<BB*NN*SEX; idx+=256){
    int b = idx/(NN*SEX), rem = idx%(NN*SEX);
    sZ[idx]  = zc [(b0+b)*NN*SEX + rem];
    sDZ[idx] = dzc[(b0+b)*NN*SEX + rem];
  }

  // Whh rows for this thread's hidden unit -> registers (3 x 60)
  float w0[SP], w1[SP], w2[SP];
  float bh0 = 0.f, bh1 = 0.f, bh2 = 0.f;
  if (n0 < SP){
    #pragma unroll
    for (int k=0;k<SP;k++){
      w0[k] = Whh[( n0     )*SP + k];
      w1[k] = Whh[( n0+ 60 )*SP + k];
      w2[k] = Whh[( n0+120 )*SP + k];
    }
    bh0 = bhh[n0]; bh1 = bhh[n0+60]; bh2 = bhh[n0+120];
    sH[0][bl][n0] = 0.f;
  }
  __syncthreads();

  float hreg = 0.f;
  int p = 0;

  auto edge_step = [&](int j){
    if (n0 < SP){
      const float* gp = gi + ((size_t)j*BATCH + bglob)*SG + n0;
      float g0 = gp[0], g1 = gp[60], g2 = gp[120];   // gi includes bih
      float blend = sHas[bl*NN + j];                 // exactly 0.0 or 1.0
      float a0 = bh0, a1 = bh1, a2 = bh2;
      const float4* h4 = (const float4*)(&sH[p][bl][0]);
      #pragma unroll
      for (int q=0;q<15;q++){
        float4 hv = h4[q];
        a0 += hv.x*w0[4*q+0]; a0 += hv.y*w0[4*q+1]; a0 += hv.z*w0[4*q+2]; a0 += hv.w*w0[4*q+3];
        a1 += hv.x*w1[4*q+0]; a1 += hv.y*w1[4*q+1]; a1 += hv.z*w1[4*q+2]; a1 += hv.w*w1[4*q+3];
        a2 += hv.x*w2[4*q+0]; a2 += hv.y*w2[4*q+1]; a2 += hv.z*w2[4*q+2]; a2 += hv.w*w2[4*q+3];
      }
      float r  = sigm(g0 + a0);
      float zg = sigm(g1 + a1);
      float nn = tanh_(g2 + r*a2);
      float hn = (1.f - zg)*nn + zg*hreg;
      hreg = hreg + blend*(hn - hreg);
      sH[p^1][bl][n0] = hreg;
    }
    __syncthreads();
    p ^= 1;
  };

  auto node_step = [&](int i){
    // rho_i from final h of node i
    if (n0 < SP){
      float acc = sBcat[n0];
      #pragma unroll
      for (int k=0;k<SP;k++) acc += sH[p][bl][k] * sWcatT[k*SP + n0];
      #pragma unroll
      for (int k=0;k<SEX;k++){
        acc += sZ [(bl*NN+i)*SEX+k] * sWcatT[(60+k)*SP + n0];
        acc += sDZ[(bl*NN+i)*SEX+k] * sWcatT[(70+k)*SP + n0];
      }
      float rv = bwd ? acc : tanh_(acc);
      sRho[bl*SP + n0] = rv;
      rho[((size_t)i*BATCH + bglob)*SP + n0] = rv;
    }
    __syncthreads();
    // gi_i = rho_i @ Wih.T + bih  (stored with bias folded in)
    if (n0 < SP){
      float a0 = sBih[n0], a1 = sBih[n0+60], a2 = sBih[n0+120];
      #pragma unroll
      for (int k=0;k<SP;k++){
        float rv = sRho[bl*SP + k];
        a0 += rv * sWihT[k*SG + n0     ];
        a1 += rv * sWihT[k*SG + n0+ 60 ];
        a2 += rv * sWihT[k*SG + n0+120 ];
      }
      float* gp = gi + ((size_t)i*BATCH + bglob)*SG + n0;
      gp[0] = a0; gp[60] = a1; gp[120] = a2;
      hreg = 0.f;
      sH[p^1][bl][n0] = 0.f;   // reset h for next node
    }
    __syncthreads();
    p ^= 1;
  };

  if (!bwd){
    for (int i=0;i<NN;i++){
      u64 w = (i==0) ? 0ULL : (sCol[i] & ((~0ULL) >> (64-i)));  // preds j<i, ascending
      while (w){
        int j = (int)__builtin_ctzll(w);
        w &= (w-1);
        edge_step(j);
      }
      node_step(i);
    }
    for (int i=NN-OO;i<NN;i++) edge_step(i);   // alpha_f: i = 56..63
  } else {
    for (int i=NN-1;i>=0;i--){
      u64 w = (i==NN-1) ? 0ULL : (sRow[i] & ((~0ULL) << (i+1)));  // succs j>i, descending
      while (w){
        int j = 63 - (int)__builtin_clzll(w);
        w &= ~(1ULL << j);
        edge_step(j);
      }
      node_step(i);
    }
    for (int i=II-1;i>=0;i--) edge_step(i);    // alpha_b: i = 7..0
  }
  if (n0 < SP) alpha[(size_t)bglob*SP + n0] = hreg;
}

// One block per batch element: psi + softmaxes, omega, value -> f32 staging.
__global__ __launch_bounds__(256, 1) void head_kernel(float* __restrict__ ws)
{
  const int b = blockIdx.x;
  const int tid = threadIdx.x;
  const float* hasc   = ws + OFF_HAS;
  const float* WaC    = ws + OFF_WA;
  const float* baC    = ws + OFF_BA;
  const float* WcC    = ws + OFF_WC;
  const float* bcC    = ws + OFF_BC;
  const float* WuC    = ws + OFF_WU;
  const float* buC    = ws + OFF_BU;
  const float* rhoF   = ws + OFF_RHOF;
  const float* rhoB   = ws + OFF_RHOB;
  const float* alphaF = ws + OFF_ALF;
  const float* alphaB = ws + OFF_ALB;
  float* stg          = ws + OFF_OSTG;

  __shared__ float sF[NN][121];        // feats, padded (odd stride -> conflict-free)
  __shared__ float sAB[120];
  __shared__ float sWu[NR*120];
  __shared__ float sHasR[NN];
  __shared__ float sPsi[NR][NN];
  __shared__ float sRed[NR][2];
  __shared__ float sOm[NA];

  for (int idx=tid; idx<NN*SP; idx+=256){
    int n = idx/SP, s = idx%SP;
    sF[n][s]    = rhoF[((size_t)n*BATCH + b)*SP + s];
    sF[n][60+s] = rhoB[((size_t)n*BATCH + b)*SP + s];
  }
  for (int idx=tid; idx<120; idx+=256)
    sAB[idx] = (idx<60) ? alphaF[(size_t)b*SP + idx] : alphaB[(size_t)b*SP + idx-60];
  for (int idx=tid; idx<NR*120; idx+=256) sWu[idx] = WuC[idx];
  for (int idx=tid; idx<NN; idx+=256) sHasR[idx] = hasc[b*NN + idx];
  __syncthreads();

  for (int idx=tid; idx<NR*NN; idx+=256){
    int r = idx/NN, n = idx%NN;
    float acc = buC[r];
    for (int s=0;s<120;s++) acc += sF[n][s]*sWu[r*120+s];
    sPsi[r][n] = (sHasR[n] != 0.f) ? acc : -60.f;
  }
  if (tid >= 64 && tid < 64+NA){
    int a = tid - 64;
    float acc = baC[a];
    for (int s=0;s<120;s++) acc += sAB[s]*WaC[a*120+s];
    sOm[a] = acc;
  }
  if (tid == 70){
    float acc = bcC[0];
    for (int s=0;s<120;s++) acc += sAB[s]*WcC[s];
    stg[2560 + BATCH*NR*NN + b] = acc;                 // value
  }
  __syncthreads();

  if (tid < NR){
    float m = -1e30f;
    for (int n=0;n<NN;n++) m = fmaxf(m, sPsi[tid][n]);
    float ssum = 0.f;
    for (int n=0;n<NN;n++) ssum += __expf(sPsi[tid][n]-m);
    sRed[tid][0] = m; sRed[tid][1] = 1.f/ssum;
  }
  if (tid == 8){
    float m = -1e30f;
    for (int a=0;a<NA;a++) m = fmaxf(m, sOm[a]);
    float e[NA]; float ssum = 0.f;
    for (int a=0;a<NA;a++){ e[a] = __expf(sOm[a]-m); ssum += e[a]; }
    for (int a=0;a<NA;a++) stg[b*NA + a] = e[a]/ssum;  // instr_prob
  }
  __syncthreads();

  for (int idx=tid; idx<NR*NN; idx+=256){
    int r = idx/NN, n = idx%NN;
    float v = __expf(sPsi[r][n]-sRed[r][0]) * sRed[r][1];
    stg[2560 + (size_t)b*NR*NN + idx] = v;             // role_prob
  }
}

extern "C" void kernel_launch(void* const* d_in, const int* in_sizes, int n_in,
                              void* d_out, int out_size, void* d_ws, size_t ws_size,
                              hipStream_t stream)
{
  const int* adj = (const int*)d_in[3];
  float* ws = (float*)d_ws;

  conv_in<<<(CONV_TOTAL+255)/256, 256, 0, stream>>>(
      d_in[0], d_in[1], d_in[2],
      d_in[4], d_in[5], d_in[6], d_in[7],
      d_in[8], d_in[9], d_in[10], d_in[11],
      d_in[12], d_in[13], d_in[14], d_in[15],
      d_in[16], d_in[17], d_in[18], d_in[19],
      d_in[20], d_in[21], ws);

  dir_kernel<<<256, 256, 0, stream>>>(adj, ws);

  head_kernel<<<512, 256, 0, stream>>>(ws);

  conv_out<<<(OUT_TOTAL+255)/256, 256, 0, stream>>>(d_in[2], ws, d_out);
}